// Round 12
// baseline (196.017 us; speedup 1.0000x reference)
//
#include <hip/hip_runtime.h>
#include <hip/hip_bf16.h>

#define S_LEN 2048
#define NF 1024
#define NH 16
#define HD 64
#define NB 2
#define M_TOT 4096  // NB*S_LEN

typedef __bf16 bf16x8 __attribute__((ext_vector_type(8)));
typedef float f32x4 __attribute__((ext_vector_type(4)));
typedef unsigned short u16;

__device__ __forceinline__ u16 f2bf(float f) {
  union { float f; unsigned u; } v; v.f = f;
  unsigned r = v.u + 0x7FFFu + ((v.u >> 16) & 1u);
  return (u16)(r >> 16);
}

__device__ __forceinline__ unsigned pk2bf(float a, float b) {
  __hip_bfloat162 t = __float22bfloat162_rn(make_float2(a, b));
  union { __hip_bfloat162 h; unsigned u; } u; u.h = t; return u.u;
}

__device__ __forceinline__ f32x4 mfma16(bf16x8 a, bf16x8 b, f32x4 c) {
  return __builtin_amdgcn_mfma_f32_16x16x32_bf16(a, b, c, 0, 0, 0);
}

// async global->LDS 16B: lds dest is wave-uniform base + lane*16
__device__ __forceinline__ void gll16(const u16* g, u16* l) {
  __builtin_amdgcn_global_load_lds(
      (const __attribute__((address_space(1))) unsigned int*)g,
      (__attribute__((address_space(3))) unsigned int*)l, 16, 0, 0);
}

// XOR-swizzled LDS addressing: 128-B rows (8 chunks of 16 B),
// chunk' = chunk ^ (row&7) -> conflict-free b128 reads (verified R2:
// SQ_LDS_BANK_CONFLICT == 0 on the GEMM path).
__device__ __forceinline__ u16* swz(u16* base, int row, int chunk) {
  return (u16*)((char*)base + row * 128 + ((chunk ^ (row & 7)) * 16));
}
__device__ __forceinline__ const u16* swz(const u16* base, int row, int chunk) {
  return (const u16*)((const char*)base + row * 128 + ((chunk ^ (row & 7)) * 16));
}

// ---- fused prologue: cast + rope table + weight transpose in ONE dispatch
//   blocks [0,4096):      cast fp32->bf16, 4 elem/thread
//   blocks [4096,4608):   rope table tab[(b*S+s)*32+p] = (sin,cos)
//   blocks [4608,8704):   weight transpose+cast, 32x32 tiles, 4 weights
__global__ void __launch_bounds__(256) prep_kernel(
    const float* __restrict__ x, u16* __restrict__ xb,
    const int* __restrict__ positions, float2* __restrict__ rtab,
    const float* __restrict__ W0, const float* __restrict__ W1,
    const float* __restrict__ W2, const float* __restrict__ W3,
    u16* __restrict__ T0, u16* __restrict__ T1,
    u16* __restrict__ T2, u16* __restrict__ T3) {
  __shared__ float t[32][33];
  const int bx = blockIdx.x, tid = threadIdx.x;
  if (bx < 4096) {
    int i = (bx * 256 + tid) * 4;
    float4 v = *(const float4*)(x + i);
    ushort4 o;
    o.x = f2bf(v.x); o.y = f2bf(v.y); o.z = f2bf(v.z); o.w = f2bf(v.w);
    *(ushort4*)(xb + i) = o;
  } else if (bx < 4608) {
    int idx = (bx - 4096) * 256 + tid;  // < NB*S_LEN*32
    int p = idx & 31;
    int bs = idx >> 5;
    float pos = (float)positions[bs];
    float ang = pos / __powf(10000.0f, (float)p * (1.0f / 32.0f));
    float sn, cs;
    sincosf(ang, &sn, &cs);
    rtab[idx] = make_float2(sn, cs);
  } else {
    int idx = bx - 4608;
    int z = idx >> 10, rem = idx & 1023;
    const float* W = (z == 0) ? W0 : (z == 1) ? W1 : (z == 2) ? W2 : W3;
    u16* Wt = (z == 0) ? T0 : (z == 1) ? T1 : (z == 2) ? T2 : T3;
    int n0 = (rem & 31) * 32, k0 = (rem >> 5) * 32;
    int tx = tid & 31, ty0 = tid >> 5;
#pragma unroll
    for (int i = 0; i < 4; i++) {
      int ty = ty0 + i * 8;
      t[ty][tx] = W[(size_t)(k0 + ty) * NF + n0 + tx];
    }
    __syncthreads();
#pragma unroll
    for (int i = 0; i < 4; i++) {
      int ty = ty0 + i * 8;
      Wt[(size_t)(n0 + ty) * NF + k0 + tx] = f2bf(t[tx][ty]);
    }
  }
}

// 128x128 tile bf16 GEMM core, BK=64, m97 2-barrier schedule (R2-proven),
// XCD-chunk block remap (R3: FETCH 72.8->28.2 MB). kstart removed (R11:
// isolated as neutral; stagger was not the over-fetch cause).
__device__ __forceinline__ void mm_core(const u16* __restrict__ A, const u16* __restrict__ Bt,
                                        int m0, int n0,
                                        u16* As, u16* Bs, f32x4 acc[4][4]) {
  const int tid = threadIdx.x;
  const int lane = tid & 63, w = tid >> 6;
  const int l15 = lane & 15, quad = lane >> 4;
  const int wr = w >> 1, wc = w & 1;
#pragma unroll
  for (int i = 0; i < 4; i++)
#pragma unroll
    for (int j = 0; j < 4; j++) {
      f32x4 z = {0.f, 0.f, 0.f, 0.f};
      acc[i][j] = z;
    }
  const u16* gA[4];
  const u16* gB[4];
#pragma unroll
  for (int i = 0; i < 4; i++) {
    int ci = i * 256 + tid;
    int row = ci >> 3, col = (ci & 7) ^ (row & 7);
    gA[i] = &A[(size_t)(m0 + row) * NF + col * 8];
    gB[i] = &Bt[(size_t)(n0 + row) * NF + col * 8];
  }
  for (int k0 = 0; k0 < NF; k0 += 64) {
    __syncthreads();  // prior step's reads done before overwrite
#pragma unroll
    for (int i = 0; i < 4; i++) {
      gll16(gA[i] + k0, &As[(i * 256 + w * 64) * 8]);
      gll16(gB[i] + k0, &Bs[(i * 256 + w * 64) * 8]);
    }
    __syncthreads();  // drain vmcnt: tile staged
#pragma unroll
    for (int kk = 0; kk < 2; kk++) {
      bf16x8 af[4], bfr[4];
#pragma unroll
      for (int i = 0; i < 4; i++)
        af[i] = *(const bf16x8*)swz(As, wr * 64 + i * 16 + l15, kk * 4 + quad);
#pragma unroll
      for (int j = 0; j < 4; j++)
        bfr[j] = *(const bf16x8*)swz(Bs, wc * 64 + j * 16 + l15, kk * 4 + quad);
#pragma unroll
      for (int i = 0; i < 4; i++)
#pragma unroll
        for (int j = 0; j < 4; j++)
          acc[i][j] = mfma16(af[i], bfr[j], acc[i][j]);
    }
  }
}

// 64x64 tile variant (for gemm_o): grid 1024 = 4 blocks/CU. 16 KB LDS.
__device__ __forceinline__ void mm_core6464(const u16* __restrict__ A, const u16* __restrict__ Bt,
                                            int m0, int n0,
                                            u16* As, u16* Bs, f32x4 acc[2][2]) {
  const int tid = threadIdx.x;
  const int lane = tid & 63, w = tid >> 6;
  const int l15 = lane & 15, quad = lane >> 4;
  const int wr = w >> 1, wc = w & 1;
#pragma unroll
  for (int i = 0; i < 2; i++)
#pragma unroll
    for (int j = 0; j < 2; j++) {
      f32x4 z = {0.f, 0.f, 0.f, 0.f};
      acc[i][j] = z;
    }
  const u16* gA[2];
  const u16* gB[2];
#pragma unroll
  for (int i = 0; i < 2; i++) {
    int ci = i * 256 + tid;  // 512 chunks each (64 rows x 8)
    int row = ci >> 3, col = (ci & 7) ^ (row & 7);
    gA[i] = &A[(size_t)(m0 + row) * NF + col * 8];
    gB[i] = &Bt[(size_t)(n0 + row) * NF + col * 8];
  }
  for (int k0 = 0; k0 < NF; k0 += 64) {
    __syncthreads();
#pragma unroll
    for (int i = 0; i < 2; i++) {
      gll16(gA[i] + k0, &As[(i * 256 + w * 64) * 8]);
      gll16(gB[i] + k0, &Bs[(i * 256 + w * 64) * 8]);
    }
    __syncthreads();
#pragma unroll
    for (int kk = 0; kk < 2; kk++) {
      bf16x8 af[2], bfr[2];
#pragma unroll
      for (int i = 0; i < 2; i++)
        af[i] = *(const bf16x8*)swz(As, wr * 32 + i * 16 + l15, kk * 4 + quad);
#pragma unroll
      for (int j = 0; j < 2; j++)
        bfr[j] = *(const bf16x8*)swz(Bs, wc * 32 + j * 16 + l15, kk * 4 + quad);
#pragma unroll
      for (int i = 0; i < 2; i++)
#pragma unroll
        for (int j = 0; j < 2; j++)
          acc[i][j] = mfma16(af[i], bfr[j], acc[i][j]);
    }
  }
}

#define QSCL 0.18033688f  // 0.125 * log2(e): folds score scale + exp->exp2 into q

// ---- fused QKV projection: z=0 -> q (rope, scaled), z=1 -> k (rope), z=2 -> v (transposed) ----
__global__ void __launch_bounds__(256) gemm_qkv_kernel(
    const u16* __restrict__ xb,
    const u16* __restrict__ wtq, const u16* __restrict__ wtk, const u16* __restrict__ wtv,
    const float* __restrict__ bq, const float* __restrict__ bk, const float* __restrict__ bv,
    const float2* __restrict__ rtab,
    u16* __restrict__ qo, u16* __restrict__ ko, u16* __restrict__ vto) {
  __shared__ u16 As[128 * 64], Bs[128 * 64];
  const int bx = blockIdx.x;
  const int xcd = bx & 7, slot = bx >> 3;
  const int z = slot >> 5, intra = slot & 31;
  const int by = (xcd >> 1) * 8 + (intra >> 2);   // m-block 0..31
  const int bxn = (xcd & 1) * 4 + (intra & 3);    // n-block 0..7
  const u16* Wt = (z == 0) ? wtq : (z == 1) ? wtk : wtv;
  const float* bias = (z == 0) ? bq : (z == 1) ? bk : bv;
  const int m0 = by * 128, n0 = bxn * 128;
  f32x4 acc[4][4];
  mm_core(xb, Wt, m0, n0, As, Bs, acc);
  const int tid = threadIdx.x;
  const int lane = tid & 63, w = tid >> 6;
  const int l15 = lane & 15, quad = lane >> 4;
  const int wr = w >> 1, wc = w & 1;
  if (z < 2) {
    u16* out = (z == 0) ? qo : ko;
    const float oscl = (z == 0) ? QSCL : 1.0f;
#pragma unroll
    for (int i = 0; i < 4; i++) {
#pragma unroll
      for (int r = 0; r < 4; r++) {
        int gm = m0 + wr * 64 + i * 16 + quad * 4 + r;  // = b*S + s
        int b = gm >> 11, s = gm & 2047;
#pragma unroll
        for (int j = 0; j < 2; j++) {
          int col1 = n0 + wc * 64 + j * 16 + l15;
          int p = j * 16 + l15;
          float2 sc = rtab[gm * 32 + p];
          float x1 = acc[i][j][r] + bias[col1];
          float x2 = acc[i][j + 2][r] + bias[col1 + 32];
          float o1 = (x1 * sc.y - x2 * sc.x) * oscl;
          float o2 = (x2 * sc.y + x1 * sc.x) * oscl;
          int h = col1 >> 6;
          size_t base = ((size_t)((b * NH + h) * S_LEN + s)) * HD;
          out[base + p] = f2bf(o1);
          out[base + p + 32] = f2bf(o2);
        }
      }
    }
  } else {
    // v: write transposed [bh][d][s]
#pragma unroll
    for (int i = 0; i < 4; i++) {
      int gm0 = m0 + wr * 64 + i * 16 + quad * 4;
      int b = gm0 >> 11, s0 = gm0 & 2047;
#pragma unroll
      for (int j = 0; j < 4; j++) {
        int col = n0 + wc * 64 + j * 16 + l15;
        int h = col >> 6, d = col & 63;
        float bb = bias[col];
        ushort4 pk;
        pk.x = f2bf(acc[i][j][0] + bb);
        pk.y = f2bf(acc[i][j][1] + bb);
        pk.z = f2bf(acc[i][j][2] + bb);
        pk.w = f2bf(acc[i][j][3] + bb);
        *(ushort4*)&vto[((size_t)((b * NH + h) * HD + d)) * S_LEN + s0] = pk;
      }
    }
  }
}

// ---- output projection: fp32 out. 64x64 tiles, 1024 blocks (4/CU). ----
__global__ void __launch_bounds__(256) gemm_o_kernel(const u16* __restrict__ ab,
                                                     const u16* __restrict__ wto,
                                                     const float* __restrict__ bo,
                                                     float* __restrict__ out) {
  __shared__ u16 As[64 * 64], Bs[64 * 64];
  const int bxr = blockIdx.x;
  const int xcd = bxr & 7, intra = bxr >> 3;  // intra in [0,128)
  const int by = xcd * 8 + (intra >> 4);      // m-block 0..63 (64-row)
  const int bxn = intra & 15;                 // n-block 0..15 (64-col)
  const int m0 = by * 64, n0 = bxn * 64;
  f32x4 acc[2][2];
  mm_core6464(ab, wto, m0, n0, As, Bs, acc);
  const int tid = threadIdx.x;
  const int lane = tid & 63, w = tid >> 6;
  const int l15 = lane & 15, quad = lane >> 4;
  const int wr = w >> 1, wc = w & 1;
#pragma unroll
  for (int i = 0; i < 2; i++) {
#pragma unroll
    for (int j = 0; j < 2; j++) {
      int col = n0 + wc * 32 + j * 16 + l15;
      float bb = bo[col];
#pragma unroll
      for (int r = 0; r < 4; r++) {
        int gm = m0 + wr * 32 + i * 16 + quad * 4 + r;
        out[(size_t)gm * NF + col] = acc[i][j][r] + bb;
      }
    }
  }
}

// ---- flash attention, causal, S^T formulation, 64-row q-tiles ----
// R12: shuffle-P. The P->LDS(ps)->wave_barrier->ds_read relayout is a pure
// lane permutation of the already-computed pk2bf words: target lane
// (quad,l15) needs P[s=hh*32+quad*8+j][q=l15], which lives in register
// pku[2hh+(quad>>1)] of lanes ((2quad)&3)*16+l15 and ((2quad+1)&3)*16+l15.
// 16 independent __shfl (ds_bpermute, pipelined, no barrier) + 8 cndmask
// replace 8 ds_write + wave_barrier + 2 ds_read + swizzle VALU; ps deleted
// (LDS 40->32 KB). Mapping verified at 4 corner cases (quad x hh).
// Rest = R10 structure: QBLK=64, 4-wave blocks, grid 1024, gll16 double-
// buffered staging, T13 defer-max (threshold 8, exp2-domain).
__global__ void __launch_bounds__(256) attn_kernel(
    const u16* __restrict__ qb, const u16* __restrict__ kb,
    const u16* __restrict__ vtb, u16* __restrict__ ob) {
  __shared__ u16 ks[2 * 64 * 64];  // [buf][s' (64)][d (64)] swizzled
  __shared__ u16 vs[2 * 64 * 64];  // [buf][d (64)][s' (64)] swizzled
  const int bx = blockIdx.x;
  // heavy-first complementary mapping: bx<512 -> qt 31..16, else qt 0..15
  const int qt = (bx < 512) ? (31 - (bx >> 5)) : ((bx - 512) >> 5);
  const int bh = bx & 31;
  const int tid = threadIdx.x;
  const int lane = tid & 63, w = tid >> 6, l15 = lane & 15, quad = lane >> 4;
  const int bb = bh >> 4, h = bh & 15;
  const size_t kvbase = (size_t)bh * S_LEN;
  const size_t vbase = (size_t)bh * HD;
  const int Q0 = qt * 64;
  const int nit = qt + 1;

  // staging geometry: each tile = 64 rows x 8 chunks of 16 B = 512 chunks;
  // thread covers chunks ci = i*256 + w*64 + lane, i<2, for K and V each.
  // source col pre-swizzled (^row&7) so linear gll16 dest matches swz reads.
  size_t kSrc[2], vSrc[2];
  int dstOff[2];
#pragma unroll
  for (int i = 0; i < 2; i++) {
    int ci = i * 256 + w * 64 + lane;
    int kr = ci >> 3, kc = ci & 7;
    kSrc[i] = (kvbase + kr) * HD + ((kc ^ (kr & 7)) * 8);
    vSrc[i] = (vbase + kr) * S_LEN + ((kc ^ (kr & 7)) * 8);
    dstOff[i] = (i * 256 + w * 64) * 8;  // wave-uniform lds base (u16 units)
  }

  bf16x8 ones;
#pragma unroll
  for (int i = 0; i < 8; i++) ones[i] = (__bf16)1.0f;

  // Q fragment (B-operand: col=l15=q, k=quad*8+j=d); wave w owns q = Q0+w*16..+15
  bf16x8 qf[2];
  {
    const u16* qrow = &qb[(kvbase + Q0 + w * 16 + l15) * HD];
#pragma unroll
    for (int hh = 0; hh < 2; hh++)
      qf[hh] = *(const bf16x8*)&qrow[hh * 32 + quad * 8];
  }

  float mrun = -1e30f;
  f32x4 Oa[4], lacc;
  { f32x4 z = {0.f, 0.f, 0.f, 0.f}; lacc = z;
#pragma unroll
    for (int t = 0; t < 4; t++) Oa[t] = z; }

  // stage first K/V tile into buf 0 (async; barrier drains vmcnt)
#pragma unroll
  for (int i = 0; i < 2; i++) {
    gll16(&kb[kSrc[i]], ks + dstOff[i]);
    gll16(&vtb[vSrc[i]], vs + dstOff[i]);
  }
  __syncthreads();

  int cur = 0;
  for (int it = 0; it < nit; ++it) {
    const int k0 = it * 64;
    const bool pf = (it + 1 < nit);
    u16* ksc = ks + cur * 4096;
    u16* vsc = vs + cur * 4096;
    if (pf) {  // async prefetch of next K/V tile into buf^1 (no regs)
      int k1 = k0 + 64;
      u16* ksn = ks + (cur ^ 1) * 4096;
      u16* vsn = vs + (cur ^ 1) * 4096;
#pragma unroll
      for (int i = 0; i < 2; i++) {
        gll16(&kb[kSrc[i] + (size_t)k1 * HD], ksn + dstOff[i]);
        gll16(&vtb[vSrc[i] + k1], vsn + dstOff[i]);
      }
    }
    // S^T = K.Q^T : 64s x 16q per wave
    f32x4 sf[4];
#pragma unroll
    for (int t = 0; t < 4; t++) {
      bf16x8 ak0 = *(const bf16x8*)swz(ksc, t * 16 + l15, quad);
      bf16x8 ak1 = *(const bf16x8*)swz(ksc, t * 16 + l15, 4 + quad);
      f32x4 z = {0.f, 0.f, 0.f, 0.f};
      z = mfma16(ak0, qf[0], z);
      z = mfma16(ak1, qf[1], z);
      sf[t] = z;
    }
    if (it == qt) {  // causal mask (diagonal tile only)
      int qg = Q0 + w * 16 + l15;
#pragma unroll
      for (int t = 0; t < 4; t++)
#pragma unroll
        for (int rr = 0; rr < 4; rr++)
          if (k0 + t * 16 + quad * 4 + rr > qg) sf[t][rr] = -1e30f;
    }
    // online softmax per q (lane-local column): in-lane max + 2 shuffles.
    // T13 defer-max: only rescale (and advance mrun) when the tile max
    // exceeds the running max by >8 (exp2-domain => P bounded by 256).
    {
      float mx = sf[0][0];
#pragma unroll
      for (int t = 0; t < 4; t++)
#pragma unroll
        for (int rr = 0; rr < 4; rr++) mx = fmaxf(mx, sf[t][rr]);
      mx = fmaxf(mx, __shfl_xor(mx, 16, 64));
      mx = fmaxf(mx, __shfl_xor(mx, 32, 64));
      if (!__all(mx <= mrun + 8.0f)) {  // wave-uniform branch
        float mnew = fmaxf(mrun, mx);
        float alph = __builtin_amdgcn_exp2f(mrun - mnew);
#pragma unroll
        for (int rr = 0; rr < 4; rr++) {
          float ao = __shfl(alph, quad * 4 + rr, 64);
#pragma unroll
          for (int t = 0; t < 4; t++) Oa[t][rr] *= ao;
          lacc[rr] *= ao;
        }
        mrun = mnew;
      }
#pragma unroll
      for (int t = 0; t < 4; t++)
#pragma unroll
        for (int rr = 0; rr < 4; rr++)
          sf[t][rr] = __builtin_amdgcn_exp2f(sf[t][rr] - mrun);
    }
    // shuffle-P: pack P to bf16 pairs, redistribute in-register (no LDS).
    unsigned pku[4][2];
#pragma unroll
    for (int t = 0; t < 4; t++) {
      pku[t][0] = pk2bf(sf[t][0], sf[t][1]);
      pku[t][1] = pk2bf(sf[t][2], sf[t][3]);
    }
    const int laneA = ((quad * 2) & 3) * 16 + l15;
    const int laneB = ((quad * 2 + 1) & 3) * 16 + l15;
    const bool hi = (quad >> 1) != 0;
    bf16x8 ap[2];
#pragma unroll
    for (int hh = 0; hh < 2; hh++) {
      unsigned a0 = __shfl((int)pku[2 * hh][0], laneA, 64);
      unsigned A0 = __shfl((int)pku[2 * hh + 1][0], laneA, 64);
      unsigned a1 = __shfl((int)pku[2 * hh][1], laneA, 64);
      unsigned A1 = __shfl((int)pku[2 * hh + 1][1], laneA, 64);
      unsigned b0 = __shfl((int)pku[2 * hh][0], laneB, 64);
      unsigned B0 = __shfl((int)pku[2 * hh + 1][0], laneB, 64);
      unsigned b1 = __shfl((int)pku[2 * hh][1], laneB, 64);
      unsigned B1 = __shfl((int)pku[2 * hh + 1][1], laneB, 64);
      union { unsigned u[4]; bf16x8 v; } cvt;
      cvt.u[0] = hi ? A0 : a0;
      cvt.u[1] = hi ? A1 : a1;
      cvt.u[2] = hi ? B0 : b0;
      cvt.u[3] = hi ? B1 : b1;
      ap[hh] = cvt.v;
    }
    // O += P.V ; l += P.1 (ones-B MFMA, lands in (quad,r) domain)
#pragma unroll
    for (int t = 0; t < 4; t++) {
      bf16x8 bv0 = *(const bf16x8*)swz(vsc, t * 16 + l15, quad);
      bf16x8 bv1 = *(const bf16x8*)swz(vsc, t * 16 + l15, 4 + quad);
      Oa[t] = mfma16(ap[0], bv0, Oa[t]);
      Oa[t] = mfma16(ap[1], bv1, Oa[t]);
    }
    lacc = mfma16(ap[0], ones, lacc);
    lacc = mfma16(ap[1], ones, lacc);
    if (pf) {
      __syncthreads();  // vmcnt(0): prefetch landed; lgkm(0): cur reads done
      cur ^= 1;
    }
  }

  // epilogue: O rows q=quad*4+rr (C-layout), cols d=t*16+l15; l per-(quad,rr)
#pragma unroll
  for (int rr = 0; rr < 4; rr++) {
    float inv = 1.f / lacc[rr];
    int qg = Q0 + w * 16 + quad * 4 + rr;
    size_t rowb = ((size_t)(bb * S_LEN + qg)) * NF + h * HD;
#pragma unroll
    for (int t = 0; t < 4; t++)
      ob[rowb + t * 16 + l15] = f2bf(Oa[t][rr] * inv);
  }
}

extern "C" void kernel_launch(void* const* d_in, const int* in_sizes, int n_in,
                              void* d_out, int out_size, void* d_ws, size_t ws_size,
                              hipStream_t stream) {
  const float* x  = (const float*)d_in[0];
  const int* pos  = (const int*)d_in[1];
  const float* Wq = (const float*)d_in[2];
  const float* bq = (const float*)d_in[3];
  const float* Wk = (const float*)d_in[4];
  const float* bk = (const float*)d_in[5];
  const float* Wv = (const float*)d_in[6];
  const float* bv = (const float*)d_in[7];
  const float* Wo = (const float*)d_in[8];
  const float* bo = (const float*)d_in[9];
  float* out = (float*)d_out;

  u16* xb  = (u16*)d_ws;                    // [M][F] bf16, reused later as attn out
  u16* wtq = xb + (size_t)M_TOT * NF;
  u16* wtk = wtq + (size_t)NF * NF;
  u16* wtv = wtk + (size_t)NF * NF;
  u16* wto = wtv + (size_t)NF * NF;
  u16* qb  = wto + (size_t)NF * NF;         // [bh][s][d] (pre-scaled by 0.125*log2e)
  u16* kb  = qb + (size_t)M_TOT * NF;       // [bh][s][d]
  u16* vtb = kb + (size_t)M_TOT * NF;       // [bh][d][s]
  float2* rtab = (float2*)(vtb + (size_t)M_TOT * NF);
  u16* attnb = xb;  // alias: xb no longer needed after QKV GEMM

  prep_kernel<<<dim3(8704), 256, 0, stream>>>(x, xb, pos, rtab,
                                              Wq, Wk, Wv, Wo, wtq, wtk, wtv, wto);
  gemm_qkv_kernel<<<dim3(768), 256, 0, stream>>>(xb, wtq, wtk, wtv, bq, bk, bv,
                                                 rtab, qb, kb, vtb);
  attn_kernel<<<dim3(1024), 256, 0, stream>>>(qb, kb, vtb, attnb);
  gemm_o_kernel<<<dim3(1024), 256, 0, stream>>>(attnb, wto, bo, out);
}

// Round 13
// 189.761 us; speedup vs baseline: 1.0330x; 1.0330x over previous
//
#include <hip/hip_runtime.h>
#include <hip/hip_bf16.h>

#define S_LEN 2048
#define NF 1024
#define NH 16
#define HD 64
#define NB 2
#define M_TOT 4096  // NB*S_LEN

typedef __bf16 bf16x8 __attribute__((ext_vector_type(8)));
typedef float f32x4 __attribute__((ext_vector_type(4)));
typedef unsigned short u16;

__device__ __forceinline__ u16 f2bf(float f) {
  union { float f; unsigned u; } v; v.f = f;
  unsigned r = v.u + 0x7FFFu + ((v.u >> 16) & 1u);
  return (u16)(r >> 16);
}

__device__ __forceinline__ unsigned pk2bf(float a, float b) {
  __hip_bfloat162 t = __float22bfloat162_rn(make_float2(a, b));
  union { __hip_bfloat162 h; unsigned u; } u; u.h = t; return u.u;
}

__device__ __forceinline__ f32x4 mfma16(bf16x8 a, bf16x8 b, f32x4 c) {
  return __builtin_amdgcn_mfma_f32_16x16x32_bf16(a, b, c, 0, 0, 0);
}

// async global->LDS 16B: lds dest is wave-uniform base + lane*16
__device__ __forceinline__ void gll16(const u16* g, u16* l) {
  __builtin_amdgcn_global_load_lds(
      (const __attribute__((address_space(1))) unsigned int*)g,
      (__attribute__((address_space(3))) unsigned int*)l, 16, 0, 0);
}

// XOR-swizzled LDS addressing: 128-B rows (8 chunks of 16 B),
// chunk' = chunk ^ (row&7) -> conflict-free b128 reads (verified R2:
// SQ_LDS_BANK_CONFLICT == 0 on the GEMM path).
__device__ __forceinline__ u16* swz(u16* base, int row, int chunk) {
  return (u16*)((char*)base + row * 128 + ((chunk ^ (row & 7)) * 16));
}
__device__ __forceinline__ const u16* swz(const u16* base, int row, int chunk) {
  return (const u16*)((const char*)base + row * 128 + ((chunk ^ (row & 7)) * 16));
}

// ---- fused prologue: cast + rope table + weight transpose in ONE dispatch
//   blocks [0,4096):      cast fp32->bf16, 4 elem/thread
//   blocks [4096,4608):   rope table tab[(b*S+s)*32+p] = (sin,cos)
//   blocks [4608,8704):   weight transpose+cast, 32x32 tiles, 4 weights
__global__ void __launch_bounds__(256) prep_kernel(
    const float* __restrict__ x, u16* __restrict__ xb,
    const int* __restrict__ positions, float2* __restrict__ rtab,
    const float* __restrict__ W0, const float* __restrict__ W1,
    const float* __restrict__ W2, const float* __restrict__ W3,
    u16* __restrict__ T0, u16* __restrict__ T1,
    u16* __restrict__ T2, u16* __restrict__ T3) {
  __shared__ float t[32][33];
  const int bx = blockIdx.x, tid = threadIdx.x;
  if (bx < 4096) {
    int i = (bx * 256 + tid) * 4;
    float4 v = *(const float4*)(x + i);
    ushort4 o;
    o.x = f2bf(v.x); o.y = f2bf(v.y); o.z = f2bf(v.z); o.w = f2bf(v.w);
    *(ushort4*)(xb + i) = o;
  } else if (bx < 4608) {
    int idx = (bx - 4096) * 256 + tid;  // < NB*S_LEN*32
    int p = idx & 31;
    int bs = idx >> 5;
    float pos = (float)positions[bs];
    float ang = pos / __powf(10000.0f, (float)p * (1.0f / 32.0f));
    float sn, cs;
    sincosf(ang, &sn, &cs);
    rtab[idx] = make_float2(sn, cs);
  } else {
    int idx = bx - 4608;
    int z = idx >> 10, rem = idx & 1023;
    const float* W = (z == 0) ? W0 : (z == 1) ? W1 : (z == 2) ? W2 : W3;
    u16* Wt = (z == 0) ? T0 : (z == 1) ? T1 : (z == 2) ? T2 : T3;
    int n0 = (rem & 31) * 32, k0 = (rem >> 5) * 32;
    int tx = tid & 31, ty0 = tid >> 5;
#pragma unroll
    for (int i = 0; i < 4; i++) {
      int ty = ty0 + i * 8;
      t[ty][tx] = W[(size_t)(k0 + ty) * NF + n0 + tx];
    }
    __syncthreads();
#pragma unroll
    for (int i = 0; i < 4; i++) {
      int ty = ty0 + i * 8;
      Wt[(size_t)(n0 + ty) * NF + k0 + tx] = f2bf(t[tx][ty]);
    }
  }
}

// 128x128 tile bf16 GEMM core, BK=64, m97 2-barrier schedule (R2-proven),
// XCD-chunk block remap (R3: FETCH 72.8->28.2 MB). kstart removed (R11:
// isolated as neutral).
__device__ __forceinline__ void mm_core(const u16* __restrict__ A, const u16* __restrict__ Bt,
                                        int m0, int n0,
                                        u16* As, u16* Bs, f32x4 acc[4][4]) {
  const int tid = threadIdx.x;
  const int lane = tid & 63, w = tid >> 6;
  const int l15 = lane & 15, quad = lane >> 4;
  const int wr = w >> 1, wc = w & 1;
#pragma unroll
  for (int i = 0; i < 4; i++)
#pragma unroll
    for (int j = 0; j < 4; j++) {
      f32x4 z = {0.f, 0.f, 0.f, 0.f};
      acc[i][j] = z;
    }
  const u16* gA[4];
  const u16* gB[4];
#pragma unroll
  for (int i = 0; i < 4; i++) {
    int ci = i * 256 + tid;
    int row = ci >> 3, col = (ci & 7) ^ (row & 7);
    gA[i] = &A[(size_t)(m0 + row) * NF + col * 8];
    gB[i] = &Bt[(size_t)(n0 + row) * NF + col * 8];
  }
  for (int k0 = 0; k0 < NF; k0 += 64) {
    __syncthreads();  // prior step's reads done before overwrite
#pragma unroll
    for (int i = 0; i < 4; i++) {
      gll16(gA[i] + k0, &As[(i * 256 + w * 64) * 8]);
      gll16(gB[i] + k0, &Bs[(i * 256 + w * 64) * 8]);
    }
    __syncthreads();  // drain vmcnt: tile staged
#pragma unroll
    for (int kk = 0; kk < 2; kk++) {
      bf16x8 af[4], bfr[4];
#pragma unroll
      for (int i = 0; i < 4; i++)
        af[i] = *(const bf16x8*)swz(As, wr * 64 + i * 16 + l15, kk * 4 + quad);
#pragma unroll
      for (int j = 0; j < 4; j++)
        bfr[j] = *(const bf16x8*)swz(Bs, wc * 64 + j * 16 + l15, kk * 4 + quad);
#pragma unroll
      for (int i = 0; i < 4; i++)
#pragma unroll
        for (int j = 0; j < 4; j++)
          acc[i][j] = mfma16(af[i], bfr[j], acc[i][j]);
    }
  }
}

// 64x64 tile variant (for gemm_o): grid 1024 = 4 blocks/CU. 16 KB LDS.
__device__ __forceinline__ void mm_core6464(const u16* __restrict__ A, const u16* __restrict__ Bt,
                                            int m0, int n0,
                                            u16* As, u16* Bs, f32x4 acc[2][2]) {
  const int tid = threadIdx.x;
  const int lane = tid & 63, w = tid >> 6;
  const int l15 = lane & 15, quad = lane >> 4;
  const int wr = w >> 1, wc = w & 1;
#pragma unroll
  for (int i = 0; i < 2; i++)
#pragma unroll
    for (int j = 0; j < 2; j++) {
      f32x4 z = {0.f, 0.f, 0.f, 0.f};
      acc[i][j] = z;
    }
  const u16* gA[2];
  const u16* gB[2];
#pragma unroll
  for (int i = 0; i < 2; i++) {
    int ci = i * 256 + tid;  // 512 chunks each (64 rows x 8)
    int row = ci >> 3, col = (ci & 7) ^ (row & 7);
    gA[i] = &A[(size_t)(m0 + row) * NF + col * 8];
    gB[i] = &Bt[(size_t)(n0 + row) * NF + col * 8];
  }
  for (int k0 = 0; k0 < NF; k0 += 64) {
    __syncthreads();
#pragma unroll
    for (int i = 0; i < 2; i++) {
      gll16(gA[i] + k0, &As[(i * 256 + w * 64) * 8]);
      gll16(gB[i] + k0, &Bs[(i * 256 + w * 64) * 8]);
    }
    __syncthreads();
#pragma unroll
    for (int kk = 0; kk < 2; kk++) {
      bf16x8 af[2], bfr[2];
#pragma unroll
      for (int i = 0; i < 2; i++)
        af[i] = *(const bf16x8*)swz(As, wr * 32 + i * 16 + l15, kk * 4 + quad);
#pragma unroll
      for (int j = 0; j < 2; j++)
        bfr[j] = *(const bf16x8*)swz(Bs, wc * 32 + j * 16 + l15, kk * 4 + quad);
#pragma unroll
      for (int i = 0; i < 2; i++)
#pragma unroll
        for (int j = 0; j < 2; j++)
          acc[i][j] = mfma16(af[i], bfr[j], acc[i][j]);
    }
  }
}

#define QSCL 0.18033688f  // 0.125 * log2(e): folds score scale + exp->exp2 into q

// ---- fused QKV projection: z=0 -> q (rope, scaled), z=1 -> k (rope), z=2 -> v (transposed) ----
__global__ void __launch_bounds__(256) gemm_qkv_kernel(
    const u16* __restrict__ xb,
    const u16* __restrict__ wtq, const u16* __restrict__ wtk, const u16* __restrict__ wtv,
    const float* __restrict__ bq, const float* __restrict__ bk, const float* __restrict__ bv,
    const float2* __restrict__ rtab,
    u16* __restrict__ qo, u16* __restrict__ ko, u16* __restrict__ vto) {
  __shared__ u16 As[128 * 64], Bs[128 * 64];
  const int bx = blockIdx.x;
  const int xcd = bx & 7, slot = bx >> 3;
  const int z = slot >> 5, intra = slot & 31;
  const int by = (xcd >> 1) * 8 + (intra >> 2);   // m-block 0..31
  const int bxn = (xcd & 1) * 4 + (intra & 3);    // n-block 0..7
  const u16* Wt = (z == 0) ? wtq : (z == 1) ? wtk : wtv;
  const float* bias = (z == 0) ? bq : (z == 1) ? bk : bv;
  const int m0 = by * 128, n0 = bxn * 128;
  f32x4 acc[4][4];
  mm_core(xb, Wt, m0, n0, As, Bs, acc);
  const int tid = threadIdx.x;
  const int lane = tid & 63, w = tid >> 6;
  const int l15 = lane & 15, quad = lane >> 4;
  const int wr = w >> 1, wc = w & 1;
  if (z < 2) {
    u16* out = (z == 0) ? qo : ko;
    const float oscl = (z == 0) ? QSCL : 1.0f;
#pragma unroll
    for (int i = 0; i < 4; i++) {
#pragma unroll
      for (int r = 0; r < 4; r++) {
        int gm = m0 + wr * 64 + i * 16 + quad * 4 + r;  // = b*S + s
        int b = gm >> 11, s = gm & 2047;
#pragma unroll
        for (int j = 0; j < 2; j++) {
          int col1 = n0 + wc * 64 + j * 16 + l15;
          int p = j * 16 + l15;
          float2 sc = rtab[gm * 32 + p];
          float x1 = acc[i][j][r] + bias[col1];
          float x2 = acc[i][j + 2][r] + bias[col1 + 32];
          float o1 = (x1 * sc.y - x2 * sc.x) * oscl;
          float o2 = (x2 * sc.y + x1 * sc.x) * oscl;
          int h = col1 >> 6;
          size_t base = ((size_t)((b * NH + h) * S_LEN + s)) * HD;
          out[base + p] = f2bf(o1);
          out[base + p + 32] = f2bf(o2);
        }
      }
    }
  } else {
    // v: write transposed [bh][d][s]
#pragma unroll
    for (int i = 0; i < 4; i++) {
      int gm0 = m0 + wr * 64 + i * 16 + quad * 4;
      int b = gm0 >> 11, s0 = gm0 & 2047;
#pragma unroll
      for (int j = 0; j < 4; j++) {
        int col = n0 + wc * 64 + j * 16 + l15;
        int h = col >> 6, d = col & 63;
        float bb = bias[col];
        ushort4 pk;
        pk.x = f2bf(acc[i][j][0] + bb);
        pk.y = f2bf(acc[i][j][1] + bb);
        pk.z = f2bf(acc[i][j][2] + bb);
        pk.w = f2bf(acc[i][j][3] + bb);
        *(ushort4*)&vto[((size_t)((b * NH + h) * HD + d)) * S_LEN + s0] = pk;
      }
    }
  }
}

// ---- output projection: fp32 out. 64x64 tiles, 1024 blocks (4/CU). ----
__global__ void __launch_bounds__(256) gemm_o_kernel(const u16* __restrict__ ab,
                                                     const u16* __restrict__ wto,
                                                     const float* __restrict__ bo,
                                                     float* __restrict__ out) {
  __shared__ u16 As[64 * 64], Bs[64 * 64];
  const int bxr = blockIdx.x;
  const int xcd = bxr & 7, intra = bxr >> 3;  // intra in [0,128)
  const int by = xcd * 8 + (intra >> 4);      // m-block 0..63 (64-row)
  const int bxn = intra & 15;                 // n-block 0..15 (64-col)
  const int m0 = by * 64, n0 = bxn * 64;
  f32x4 acc[2][2];
  mm_core6464(ab, wto, m0, n0, As, Bs, acc);
  const int tid = threadIdx.x;
  const int lane = tid & 63, w = tid >> 6;
  const int l15 = lane & 15, quad = lane >> 4;
  const int wr = w >> 1, wc = w & 1;
#pragma unroll
  for (int i = 0; i < 2; i++) {
#pragma unroll
    for (int j = 0; j < 2; j++) {
      int col = n0 + wc * 32 + j * 16 + l15;
      float bb = bo[col];
#pragma unroll
      for (int r = 0; r < 4; r++) {
        int gm = m0 + wr * 32 + i * 16 + quad * 4 + r;
        out[(size_t)gm * NF + col] = acc[i][j][r] + bb;
      }
    }
  }
}

// ---- flash attention, causal, S^T formulation, 64-row q-tiles ----
// R13: REVERT shuffle-P (R12 regression: __shfl == ds_bpermute on CDNA,
// i.e. LDS-crossbar traffic -- 16 narrow gather ops replaced 10 wide
// wave-local conflict-free ops; SQ_LDS_BANK_CONFLICT doubled, attn +8us).
// Back to R10/R11-proven ps-LDS relayout. Structure: QBLK=64, 4-wave
// blocks, grid 1024, gll16 double-buffered staging, T13 defer-max.
__global__ void __launch_bounds__(256) attn_kernel(
    const u16* __restrict__ qb, const u16* __restrict__ kb,
    const u16* __restrict__ vtb, u16* __restrict__ ob) {
  __shared__ u16 ks[2 * 64 * 64];  // [buf][s' (64)][d (64)] swizzled
  __shared__ u16 vs[2 * 64 * 64];  // [buf][d (64)][s' (64)] swizzled
  __shared__ u16 ps[4][16 * 64];   // per-wave P relayout (2 KB each)
  const int bx = blockIdx.x;
  // heavy-first complementary mapping: bx<512 -> qt 31..16, else qt 0..15
  const int qt = (bx < 512) ? (31 - (bx >> 5)) : ((bx - 512) >> 5);
  const int bh = bx & 31;
  const int tid = threadIdx.x;
  const int lane = tid & 63, w = tid >> 6, l15 = lane & 15, quad = lane >> 4;
  const int bb = bh >> 4, h = bh & 15;
  const size_t kvbase = (size_t)bh * S_LEN;
  const size_t vbase = (size_t)bh * HD;
  const int Q0 = qt * 64;
  const int nit = qt + 1;

  // staging geometry: each tile = 64 rows x 8 chunks of 16 B = 512 chunks;
  // thread covers chunks ci = i*256 + w*64 + lane, i<2, for K and V each.
  // source col pre-swizzled (^row&7) so linear gll16 dest matches swz reads.
  size_t kSrc[2], vSrc[2];
  int dstOff[2];
#pragma unroll
  for (int i = 0; i < 2; i++) {
    int ci = i * 256 + w * 64 + lane;
    int kr = ci >> 3, kc = ci & 7;
    kSrc[i] = (kvbase + kr) * HD + ((kc ^ (kr & 7)) * 8);
    vSrc[i] = (vbase + kr) * S_LEN + ((kc ^ (kr & 7)) * 8);
    dstOff[i] = (i * 256 + w * 64) * 8;  // wave-uniform lds base (u16 units)
  }

  bf16x8 ones;
#pragma unroll
  for (int i = 0; i < 8; i++) ones[i] = (__bf16)1.0f;

  // Q fragment (B-operand: col=l15=q, k=quad*8+j=d); wave w owns q = Q0+w*16..+15
  bf16x8 qf[2];
  {
    const u16* qrow = &qb[(kvbase + Q0 + w * 16 + l15) * HD];
#pragma unroll
    for (int hh = 0; hh < 2; hh++)
      qf[hh] = *(const bf16x8*)&qrow[hh * 32 + quad * 8];
  }

  float mrun = -1e30f;
  f32x4 Oa[4], lacc;
  { f32x4 z = {0.f, 0.f, 0.f, 0.f}; lacc = z;
#pragma unroll
    for (int t = 0; t < 4; t++) Oa[t] = z; }

  // stage first K/V tile into buf 0 (async; barrier drains vmcnt)
#pragma unroll
  for (int i = 0; i < 2; i++) {
    gll16(&kb[kSrc[i]], ks + dstOff[i]);
    gll16(&vtb[vSrc[i]], vs + dstOff[i]);
  }
  __syncthreads();

  int cur = 0;
  for (int it = 0; it < nit; ++it) {
    const int k0 = it * 64;
    const bool pf = (it + 1 < nit);
    u16* ksc = ks + cur * 4096;
    u16* vsc = vs + cur * 4096;
    if (pf) {  // async prefetch of next K/V tile into buf^1 (no regs)
      int k1 = k0 + 64;
      u16* ksn = ks + (cur ^ 1) * 4096;
      u16* vsn = vs + (cur ^ 1) * 4096;
#pragma unroll
      for (int i = 0; i < 2; i++) {
        gll16(&kb[kSrc[i] + (size_t)k1 * HD], ksn + dstOff[i]);
        gll16(&vtb[vSrc[i] + k1], vsn + dstOff[i]);
      }
    }
    // S^T = K.Q^T : 64s x 16q per wave
    f32x4 sf[4];
#pragma unroll
    for (int t = 0; t < 4; t++) {
      bf16x8 ak0 = *(const bf16x8*)swz(ksc, t * 16 + l15, quad);
      bf16x8 ak1 = *(const bf16x8*)swz(ksc, t * 16 + l15, 4 + quad);
      f32x4 z = {0.f, 0.f, 0.f, 0.f};
      z = mfma16(ak0, qf[0], z);
      z = mfma16(ak1, qf[1], z);
      sf[t] = z;
    }
    if (it == qt) {  // causal mask (diagonal tile only)
      int qg = Q0 + w * 16 + l15;
#pragma unroll
      for (int t = 0; t < 4; t++)
#pragma unroll
        for (int rr = 0; rr < 4; rr++)
          if (k0 + t * 16 + quad * 4 + rr > qg) sf[t][rr] = -1e30f;
    }
    // online softmax per q (lane-local column): in-lane max + 2 shuffles.
    // T13 defer-max: only rescale (and advance mrun) when the tile max
    // exceeds the running max by >8 (exp2-domain => P bounded by 256).
    {
      float mx = sf[0][0];
#pragma unroll
      for (int t = 0; t < 4; t++)
#pragma unroll
        for (int rr = 0; rr < 4; rr++) mx = fmaxf(mx, sf[t][rr]);
      mx = fmaxf(mx, __shfl_xor(mx, 16, 64));
      mx = fmaxf(mx, __shfl_xor(mx, 32, 64));
      if (!__all(mx <= mrun + 8.0f)) {  // wave-uniform branch
        float mnew = fmaxf(mrun, mx);
        float alph = __builtin_amdgcn_exp2f(mrun - mnew);
#pragma unroll
        for (int rr = 0; rr < 4; rr++) {
          float ao = __shfl(alph, quad * 4 + rr, 64);
#pragma unroll
          for (int t = 0; t < 4; t++) Oa[t][rr] *= ao;
          lacc[rr] *= ao;
        }
        mrun = mnew;
      }
#pragma unroll
      for (int t = 0; t < 4; t++)
#pragma unroll
        for (int rr = 0; rr < 4; rr++)
          sf[t][rr] = __builtin_amdgcn_exp2f(sf[t][rr] - mrun);
    }
    // P -> LDS in A-layout [q][s], b64 packed (wave-local; DS in-order/wave)
#pragma unroll
    for (int t = 0; t < 4; t++) {
      uint2 pkk;
      pkk.x = pk2bf(sf[t][0], sf[t][1]);
      pkk.y = pk2bf(sf[t][2], sf[t][3]);
      int chnk = 2 * t + (quad >> 1);
      *(uint2*)((char*)ps[w] + l15 * 128 + ((chnk ^ (l15 & 7)) * 16) + (quad & 1) * 8) = pkk;
    }
    __builtin_amdgcn_wave_barrier();
    bf16x8 ap[2];
#pragma unroll
    for (int hh = 0; hh < 2; hh++)
      ap[hh] = *(const bf16x8*)swz(ps[w], l15, hh * 4 + quad);
    // O += P.V ; l += P.1 (ones-B MFMA, lands in (quad,r) domain)
#pragma unroll
    for (int t = 0; t < 4; t++) {
      bf16x8 bv0 = *(const bf16x8*)swz(vsc, t * 16 + l15, quad);
      bf16x8 bv1 = *(const bf16x8*)swz(vsc, t * 16 + l15, 4 + quad);
      Oa[t] = mfma16(ap[0], bv0, Oa[t]);
      Oa[t] = mfma16(ap[1], bv1, Oa[t]);
    }
    lacc = mfma16(ap[0], ones, lacc);
    lacc = mfma16(ap[1], ones, lacc);
    if (pf) {
      __syncthreads();  // vmcnt(0): prefetch landed; lgkm(0): cur reads done
      cur ^= 1;
    }
  }

  // epilogue: O rows q=quad*4+rr (C-layout), cols d=t*16+l15; l per-(quad,rr)
#pragma unroll
  for (int rr = 0; rr < 4; rr++) {
    float inv = 1.f / lacc[rr];
    int qg = Q0 + w * 16 + quad * 4 + rr;
    size_t rowb = ((size_t)(bb * S_LEN + qg)) * NF + h * HD;
#pragma unroll
    for (int t = 0; t < 4; t++)
      ob[rowb + t * 16 + l15] = f2bf(Oa[t][rr] * inv);
  }
}

extern "C" void kernel_launch(void* const* d_in, const int* in_sizes, int n_in,
                              void* d_out, int out_size, void* d_ws, size_t ws_size,
                              hipStream_t stream) {
  const float* x  = (const float*)d_in[0];
  const int* pos  = (const int*)d_in[1];
  const float* Wq = (const float*)d_in[2];
  const float* bq = (const float*)d_in[3];
  const float* Wk = (const float*)d_in[4];
  const float* bk = (const float*)d_in[5];
  const float* Wv = (const float*)d_in[6];
  const float* bv = (const float*)d_in[7];
  const float* Wo = (const float*)d_in[8];
  const float* bo = (const float*)d_in[9];
  float* out = (float*)d_out;

  u16* xb  = (u16*)d_ws;                    // [M][F] bf16, reused later as attn out
  u16* wtq = xb + (size_t)M_TOT * NF;
  u16* wtk = wtq + (size_t)NF * NF;
  u16* wtv = wtk + (size_t)NF * NF;
  u16* wto = wtv + (size_t)NF * NF;
  u16* qb  = wto + (size_t)NF * NF;         // [bh][s][d] (pre-scaled by 0.125*log2e)
  u16* kb  = qb + (size_t)M_TOT * NF;       // [bh][s][d]
  u16* vtb = kb + (size_t)M_TOT * NF;       // [bh][d][s]
  float2* rtab = (float2*)(vtb + (size_t)M_TOT * NF);
  u16* attnb = xb;  // alias: xb no longer needed after QKV GEMM

  prep_kernel<<<dim3(8704), 256, 0, stream>>>(x, xb, pos, rtab,
                                              Wq, Wk, Wv, Wo, wtq, wtk, wtv, wto);
  gemm_qkv_kernel<<<dim3(768), 256, 0, stream>>>(xb, wtq, wtk, wtv, bq, bk, bv,
                                                 rtab, qb, kb, vtb);
  attn_kernel<<<dim3(1024), 256, 0, stream>>>(qb, kb, vtb, attnb);
  gemm_o_kernel<<<dim3(1024), 256, 0, stream>>>(attnb, wto, bo, out);
}